// Round 1
// baseline (192.654 us; speedup 1.0000x reference)
//
#include <hip/hip_runtime.h>
#include <hip/hip_bf16.h>

// Chamfer loss, B=8, N=M=8192, D=3, fp32.
// result = (mean_n min_m d2(a_n,b_m) + mean_m min_n d2) / 2
// d2 = a2 + b2 - 2ab; we track max_q where q = ab - 0.5*b2, then
// d2_min = max(a2 - 2*max_q, 0).

#define BATCH   8
#define NPTS    8192
#define NCHUNK  4          // m-split
#define CHUNK   (NPTS / NCHUNK)   // 2048
#define IL      8          // a-points per thread
#define BLK     256
#define PTS_PER_BLK (BLK * IL)    // 2048
#define NB      (NPTS / PTS_PER_BLK) // 4
#define TOTAL_A (2 * BATCH * NPTS)   // 131072
#define P2_BLOCKS (TOTAL_A / BLK)    // 512

__global__ __launch_bounds__(BLK) void chamfer_pass1(
    const float* __restrict__ pred, const float* __restrict__ gt,
    float* __restrict__ partial) {
  __shared__ float4 bs[CHUNK];   // 32 KB

  const int bid   = blockIdx.x;
  const int chunk = bid & (NCHUNK - 1);
  const int nb    = (bid >> 2) & (NB - 1);
  const int batch = (bid >> 4) & (BATCH - 1);
  const int side  = bid >> 7;

  const float* A  = (side == 0) ? pred : gt;
  const float* Bp = (side == 0) ? gt : pred;
  const int t = threadIdx.x;

  // stage b-chunk into LDS as (x, y, z, 0.5*|b|^2)
  const float* bbase = Bp + ((size_t)batch * NPTS + (size_t)chunk * CHUNK) * 3;
  for (int p = t; p < CHUNK; p += BLK) {
    float bx = bbase[p * 3 + 0];
    float by = bbase[p * 3 + 1];
    float bz = bbase[p * 3 + 2];
    bs[p] = make_float4(bx, by, bz, 0.5f * (bx * bx + by * by + bz * bz));
  }
  __syncthreads();

  // load IL a-points per thread
  float ax[IL], ay[IL], az[IL], mq[IL];
  const float* abase = A + ((size_t)batch * NPTS + (size_t)nb * PTS_PER_BLK) * 3;
#pragma unroll
  for (int i = 0; i < IL; i++) {
    int n = i * BLK + t;
    ax[i] = abase[n * 3 + 0];
    ay[i] = abase[n * 3 + 1];
    az[i] = abase[n * 3 + 2];
    mq[i] = -1e30f;
  }

  // main loop: LDS broadcast read + 8x(3 FMA + max)
#pragma unroll 4
  for (int j = 0; j < CHUNK; j++) {
    float4 bp = bs[j];
#pragma unroll
    for (int i = 0; i < IL; i++) {
      float q = fmaf(ax[i], bp.x, fmaf(ay[i], bp.y, fmaf(az[i], bp.z, -bp.w)));
      mq[i] = fmaxf(mq[i], q);
    }
  }

  // partial layout: [((side*BATCH+batch)*NPTS + n) * NCHUNK + chunk]
#pragma unroll
  for (int i = 0; i < IL; i++) {
    int n = nb * PTS_PER_BLK + i * BLK + t;
    size_t idx = ((size_t)(side * BATCH + batch) * NPTS + n) * NCHUNK + chunk;
    partial[idx] = mq[i];
  }
}

__global__ __launch_bounds__(BLK) void chamfer_pass2(
    const float* __restrict__ pred, const float* __restrict__ gt,
    const float4* __restrict__ partial, float* __restrict__ blockSums) {
  const int gid  = blockIdx.x * BLK + threadIdx.x;   // [0, TOTAL_A)
  const int side = gid >> 16;                        // BATCH*NPTS == 65536
  const int rem  = gid & 65535;                      // batch*NPTS + n

  const float* A = (side == 0) ? pred : gt;
  float x = A[(size_t)rem * 3 + 0];
  float y = A[(size_t)rem * 3 + 1];
  float z = A[(size_t)rem * 3 + 2];
  float a2 = fmaf(x, x, fmaf(y, y, z * z));

  float4 p = partial[gid];   // the 4 chunk partials, contiguous
  float mq = fmaxf(fmaxf(p.x, p.y), fmaxf(p.z, p.w));
  float d2 = fmaxf(fmaf(-2.0f, mq, a2), 0.0f);

  // block reduction: wave shuffle then LDS across 4 waves
  float v = d2;
  for (int off = 32; off > 0; off >>= 1) v += __shfl_down(v, off);
  __shared__ float wsum[BLK / 64];
  int lane = threadIdx.x & 63, wv = threadIdx.x >> 6;
  if (lane == 0) wsum[wv] = v;
  __syncthreads();
  if (wv == 0) {
    float s = (lane < (BLK / 64)) ? wsum[lane] : 0.0f;
    for (int off = 2; off > 0; off >>= 1) s += __shfl_down(s, off);
    if (lane == 0) blockSums[blockIdx.x] = s;
  }
}

__global__ __launch_bounds__(BLK) void chamfer_pass3(
    const float* __restrict__ blockSums, float* __restrict__ out) {
  const int t = threadIdx.x;
  float v = blockSums[t] + blockSums[t + BLK];   // 512 sums
  for (int off = 32; off > 0; off >>= 1) v += __shfl_down(v, off);
  __shared__ float wsum[BLK / 64];
  int lane = t & 63, wv = t >> 6;
  if (lane == 0) wsum[wv] = v;
  __syncthreads();
  if (t == 0) {
    float s = wsum[0] + wsum[1] + wsum[2] + wsum[3];
    // (sum1/65536 + sum2/65536) / 2 == total / 131072
    out[0] = s * (1.0f / (float)TOTAL_A);
  }
}

extern "C" void kernel_launch(void* const* d_in, const int* in_sizes, int n_in,
                              void* d_out, int out_size, void* d_ws, size_t ws_size,
                              hipStream_t stream) {
  const float* pred = (const float*)d_in[0];
  const float* gt   = (const float*)d_in[1];
  float* out = (float*)d_out;

  float* partial   = (float*)d_ws;                       // TOTAL_A * NCHUNK floats = 2 MB
  float* blockSums = partial + (size_t)TOTAL_A * NCHUNK; // + 512 floats

  const int p1_blocks = 2 * BATCH * NB * NCHUNK;         // 256
  chamfer_pass1<<<p1_blocks, BLK, 0, stream>>>(pred, gt, partial);
  chamfer_pass2<<<P2_BLOCKS, BLK, 0, stream>>>(pred, gt, (const float4*)partial, blockSums);
  chamfer_pass3<<<1, BLK, 0, stream>>>(blockSums, out);
}

// Round 2
// 141.982 us; speedup vs baseline: 1.3569x; 1.3569x over previous
//
#include <hip/hip_runtime.h>
#include <hip/hip_bf16.h>

// Chamfer loss, B=8, N=M=8192, D=3, fp32.
// result = (mean_n min_m d2(a_n,b_m) + mean_m min_n d2) / 2
// d2 = a2 + b2 - 2ab; track max_q where q = ab - 0.5*b2, then
// d2_min = max(a2 - 2*max_q, 0).
//
// R2: occupancy fix — 1024 blocks (4/CU, 4 waves/SIMD) via NCHUNK=16,
// plus 2-wide j-step with v_max3_f32 fusion (7 insts / 2 pairs).

#define BATCH   8
#define NPTS    8192
#define IL      8                     // a-points per thread
#define BLK     256
#define PTS_PER_BLK (BLK * IL)        // 2048
#define NB      (NPTS / PTS_PER_BLK)  // 4
#define TOTAL_A (2 * BATCH * NPTS)    // 131072
#define P2_BLOCKS (TOTAL_A / BLK)     // 512

template <int NCH>
__global__ __launch_bounds__(BLK) void chamfer_pass1_t(
    const float* __restrict__ pred, const float* __restrict__ gt,
    float* __restrict__ partial) {
  constexpr int CH = NPTS / NCH;      // b-points per chunk
  __shared__ float4 bs[CH];

  const int bid   = blockIdx.x;
  const int chunk = bid & (NCH - 1);
  const int r     = bid / NCH;        // NCH is pow2 -> shift
  const int nb    = r & (NB - 1);
  const int batch = (r >> 2) & (BATCH - 1);
  const int side  = r >> 5;

  const float* A  = (side == 0) ? pred : gt;
  const float* Bp = (side == 0) ? gt : pred;
  const int t = threadIdx.x;

  // stage b-chunk into LDS as (x, y, z, 0.5*|b|^2)
  const float* bbase = Bp + ((size_t)batch * NPTS + (size_t)chunk * CH) * 3;
  for (int p = t; p < CH; p += BLK) {
    float bx = bbase[p * 3 + 0];
    float by = bbase[p * 3 + 1];
    float bz = bbase[p * 3 + 2];
    bs[p] = make_float4(bx, by, bz, 0.5f * (bx * bx + by * by + bz * bz));
  }
  __syncthreads();

  // load IL a-points per thread
  float ax[IL], ay[IL], az[IL], mq[IL];
  const float* abase = A + ((size_t)batch * NPTS + (size_t)nb * PTS_PER_BLK) * 3;
#pragma unroll
  for (int i = 0; i < IL; i++) {
    int n = i * BLK + t;
    ax[i] = abase[n * 3 + 0];
    ay[i] = abase[n * 3 + 1];
    az[i] = abase[n * 3 + 2];
    mq[i] = -1e30f;
  }

  // main loop: 2 broadcast LDS reads + IL*(6 FMA + 1 max3) per step
#pragma unroll 2
  for (int j = 0; j < CH; j += 2) {
    float4 b0 = bs[j];
    float4 b1 = bs[j + 1];
#pragma unroll
    for (int i = 0; i < IL; i++) {
      float q0 = fmaf(ax[i], b0.x, fmaf(ay[i], b0.y, fmaf(az[i], b0.z, -b0.w)));
      float q1 = fmaf(ax[i], b1.x, fmaf(ay[i], b1.y, fmaf(az[i], b1.z, -b1.w)));
      mq[i] = fmaxf(fmaxf(q0, q1), mq[i]);   // -> v_max3_f32
    }
  }

  // partial layout: [((side*BATCH+batch)*NPTS + n) * NCH + chunk]
#pragma unroll
  for (int i = 0; i < IL; i++) {
    int n = nb * PTS_PER_BLK + i * BLK + t;
    size_t idx = ((size_t)(side * BATCH + batch) * NPTS + n) * NCH + chunk;
    partial[idx] = mq[i];
  }
}

template <int NCH>
__global__ __launch_bounds__(BLK) void chamfer_pass2_t(
    const float* __restrict__ pred, const float* __restrict__ gt,
    const float4* __restrict__ partial, float* __restrict__ blockSums) {
  const int gid  = blockIdx.x * BLK + threadIdx.x;   // [0, TOTAL_A)
  const int side = gid >> 16;                        // BATCH*NPTS == 65536
  const int rem  = gid & 65535;                      // batch*NPTS + n

  const float* A = (side == 0) ? pred : gt;
  float x = A[(size_t)rem * 3 + 0];
  float y = A[(size_t)rem * 3 + 1];
  float z = A[(size_t)rem * 3 + 2];
  float a2 = fmaf(x, x, fmaf(y, y, z * z));

  float mq = -1e30f;
#pragma unroll
  for (int c = 0; c < NCH / 4; c++) {
    float4 p = partial[(size_t)gid * (NCH / 4) + c];
    mq = fmaxf(fmaxf(fmaxf(p.x, p.y), fmaxf(p.z, p.w)), mq);
  }
  float d2 = fmaxf(fmaf(-2.0f, mq, a2), 0.0f);

  // block reduction: wave shuffle then LDS across 4 waves
  float v = d2;
  for (int off = 32; off > 0; off >>= 1) v += __shfl_down(v, off);
  __shared__ float wsum[BLK / 64];
  int lane = threadIdx.x & 63, wv = threadIdx.x >> 6;
  if (lane == 0) wsum[wv] = v;
  __syncthreads();
  if (wv == 0) {
    float s = (lane < (BLK / 64)) ? wsum[lane] : 0.0f;
    for (int off = 2; off > 0; off >>= 1) s += __shfl_down(s, off);
    if (lane == 0) blockSums[blockIdx.x] = s;
  }
}

__global__ __launch_bounds__(BLK) void chamfer_pass3(
    const float* __restrict__ blockSums, float* __restrict__ out) {
  const int t = threadIdx.x;
  float v = blockSums[t] + blockSums[t + BLK];   // 512 sums
  for (int off = 32; off > 0; off >>= 1) v += __shfl_down(v, off);
  __shared__ float wsum[BLK / 64];
  int lane = t & 63, wv = t >> 6;
  if (lane == 0) wsum[wv] = v;
  __syncthreads();
  if (t == 0) {
    float s = wsum[0] + wsum[1] + wsum[2] + wsum[3];
    out[0] = s * (1.0f / (float)TOTAL_A);   // (sum1+sum2)/(2*65536)
  }
}

extern "C" void kernel_launch(void* const* d_in, const int* in_sizes, int n_in,
                              void* d_out, int out_size, void* d_ws, size_t ws_size,
                              hipStream_t stream) {
  const float* pred = (const float*)d_in[0];
  const float* gt   = (const float*)d_in[1];
  float* out = (float*)d_out;

  float* partial = (float*)d_ws;
  const size_t need16 = (size_t)TOTAL_A * 16 * sizeof(float) + 4096;  // 8 MB + slack

  if (ws_size >= need16) {
    constexpr int NCH = 16;
    float* blockSums = partial + (size_t)TOTAL_A * NCH;
    const int p1_blocks = 2 * BATCH * NB * NCH;   // 1024
    chamfer_pass1_t<NCH><<<p1_blocks, BLK, 0, stream>>>(pred, gt, partial);
    chamfer_pass2_t<NCH><<<P2_BLOCKS, BLK, 0, stream>>>(pred, gt, (const float4*)partial, blockSums);
    chamfer_pass3<<<1, BLK, 0, stream>>>(blockSums, out);
  } else {
    constexpr int NCH = 4;                        // 2 MB fallback (known-good)
    float* blockSums = partial + (size_t)TOTAL_A * NCH;
    const int p1_blocks = 2 * BATCH * NB * NCH;   // 256
    chamfer_pass1_t<NCH><<<p1_blocks, BLK, 0, stream>>>(pred, gt, partial);
    chamfer_pass2_t<NCH><<<P2_BLOCKS, BLK, 0, stream>>>(pred, gt, (const float4*)partial, blockSums);
    chamfer_pass3<<<1, BLK, 0, stream>>>(blockSums, out);
  }
}